// Round 1
// baseline (1613.997 us; speedup 1.0000x reference)
//
#include <hip/hip_runtime.h>
#include <hip/hip_bf16.h>
#include <stdint.h>

// Problem constants (B,S,H,V,L from reference)
#define Bn 8
#define Sn 128
#define Hn 512
#define Vn 32000
#define Ln 20

typedef __attribute__((ext_vector_type(8))) short bf16x8;   // 8 bf16 = 4 VGPRs
typedef __attribute__((ext_vector_type(4))) float f32x4;    // MFMA acc

static __device__ __forceinline__ short f2bf(float f) {
    // round-to-nearest-even fp32 -> bf16
    union { float f; uint32_t u; } x; x.f = f;
    uint32_t r = x.u + 0x7FFFu + ((x.u >> 16) & 1u);
    return (short)(r >> 16);
}

// Kernel 1: linfo[b][h] = dot(length_table[idx[b]], proj_W[h]) + proj_b[h]
// one wave per (b,h); 8*512 = 4096 waves -> 1024 blocks of 256
__global__ void linfo_kernel(const int* __restrict__ ans,
                             const float* __restrict__ length_table,
                             const float* __restrict__ proj_W,
                             const float* __restrict__ proj_b,
                             float* __restrict__ linfo)
{
    int gw   = (blockIdx.x * blockDim.x + threadIdx.x) >> 6;
    int lane = threadIdx.x & 63;
    int b = gw >> 9;        // /512
    int h = gw & (Hn - 1);
    int idx = ans[b];
    idx = idx < 1 ? 1 : (idx > Ln ? Ln : idx);
    const float* le = length_table + (size_t)idx * Hn;
    const float* wr = proj_W + (size_t)h * Hn;
    float s = 0.f;
    #pragma unroll
    for (int j = 0; j < Hn; j += 64) s += le[j + lane] * wr[j + lane];
    #pragma unroll
    for (int off = 32; off > 0; off >>= 1) s += __shfl_down(s, off);
    if (lane == 0) linfo[b * Hn + h] = s + proj_b[h];
}

// Kernel 2: enhanced (bf16) = hidden + linfo broadcast; 4 elems/thread
__global__ void enh_kernel(const float* __restrict__ hidden,
                           const float* __restrict__ linfo,
                           short* __restrict__ enh)
{
    int i = (blockIdx.x * blockDim.x + threadIdx.x) * 4;
    int b = i >> 16;             // /(S*H = 65536)
    int h = i & (Hn - 1);
    float4 hv = *(const float4*)(hidden + i);
    float4 lv = *(const float4*)(linfo + b * Hn + h);
    short4 ev = make_short4(f2bf(hv.x + lv.x), f2bf(hv.y + lv.y),
                            f2bf(hv.z + lv.z), f2bf(hv.w + lv.w));
    *(short4*)(enh + i) = ev;
}

// Kernel 3: per-batch GEMM  out[b][s][v] = sum_h enh[b][s][h] * W[idx[b]][v][h] + bias[idx[b]][v]
// 128x128 block tile, BK=32, 4 waves each computing 64x64 via 4x4 16x16x32 bf16 MFMAs.
// grid = (V/128 = 250, B = 8), block = 256
__global__ __launch_bounds__(256) void
gemm_kernel(const short* __restrict__ enh,
            const float* __restrict__ heads_W,
            const float* __restrict__ heads_b,
            const int*  __restrict__ ans,
            float* __restrict__ out)
{
    __shared__ short As[128 * 32];   // A tile bf16 (rows = s, cols = k)
    __shared__ short Bs[128 * 32];   // W tile bf16 (rows = v, cols = k)

    const int b    = blockIdx.y;
    const int col0 = blockIdx.x * 128;

    int idx = ans[b];
    idx = idx < 1 ? 1 : (idx > Ln ? Ln : idx);

    const float* Wb = heads_W + (size_t)idx * Vn * Hn;
    const short* Ab = enh + (size_t)b * Sn * Hn;

    const int tid  = threadIdx.x;
    const int lane = tid & 63;
    const int w    = tid >> 6;
    const int wm   = w >> 1;    // wave row  {0,1}
    const int wn   = w & 1;     // wave col  {0,1}
    const int quad = lane >> 4; // 0..3
    const int r    = lane & 15;

    f32x4 acc[4][4] = {};

    for (int k0 = 0; k0 < Hn; k0 += 32) {
        __syncthreads();   // protect LDS from previous iteration's reads

        // ---- stage A: 128x32 bf16 = 8 KB; 512 units of 16 B; 2 per thread
        #pragma unroll
        for (int l = 0; l < 2; ++l) {
            int u   = tid + l * 256;
            int row = u >> 2;           // 0..127
            int col = (u & 3) << 3;     // 0,8,16,24
            *(int4*)(&As[u * 8]) = *(const int4*)(Ab + row * Hn + k0 + col);
        }

        // ---- stage W: 128x32 fp32 -> bf16; 1024 float4 units; 4 per thread
        #pragma unroll
        for (int l = 0; l < 4; ++l) {
            int u    = tid + l * 256;
            int row  = u >> 3;          // 0..127 (v within tile)
            int colf = (u & 7) << 2;    // 0,4,...,28
            float4 wv = *(const float4*)(Wb + (size_t)(col0 + row) * Hn + k0 + colf);
            short4 sv = make_short4(f2bf(wv.x), f2bf(wv.y), f2bf(wv.z), f2bf(wv.w));
            *(short4*)(&Bs[row * 32 + colf]) = sv;
        }
        __syncthreads();

        // ---- fragments + MFMA
        bf16x8 af[4], bfr[4];
        #pragma unroll
        for (int mi = 0; mi < 4; ++mi)
            af[mi] = *(const bf16x8*)(&As[(wm * 64 + mi * 16 + r) * 32 + quad * 8]);
        #pragma unroll
        for (int ni = 0; ni < 4; ++ni)
            bfr[ni] = *(const bf16x8*)(&Bs[(wn * 64 + ni * 16 + r) * 32 + quad * 8]);
        #pragma unroll
        for (int mi = 0; mi < 4; ++mi)
            #pragma unroll
            for (int ni = 0; ni < 4; ++ni)
                acc[mi][ni] = __builtin_amdgcn_mfma_f32_16x16x32_bf16(
                    af[mi], bfr[ni], acc[mi][ni], 0, 0, 0);
    }

    // ---- epilogue: C/D layout col=lane&15, row=quad*4+reg
    const float* bias = heads_b + (size_t)idx * Vn;
    float* outb = out + (size_t)b * Sn * Vn;
    #pragma unroll
    for (int ni = 0; ni < 4; ++ni) {
        int v = col0 + wn * 64 + ni * 16 + r;
        float bv = bias[v];
        #pragma unroll
        for (int mi = 0; mi < 4; ++mi) {
            int srow = wm * 64 + mi * 16 + quad * 4;
            #pragma unroll
            for (int reg = 0; reg < 4; ++reg)
                outb[(size_t)(srow + reg) * Vn + v] = acc[mi][ni][reg] + bv;
        }
    }
}

extern "C" void kernel_launch(void* const* d_in, const int* in_sizes, int n_in,
                              void* d_out, int out_size, void* d_ws, size_t ws_size,
                              hipStream_t stream) {
    const float* hidden       = (const float*)d_in[0];  // [8,128,512]
    const int*   answer_len   = (const int*)  d_in[1];  // [8]
    const float* length_table = (const float*)d_in[2];  // [21,512]
    const float* proj_W       = (const float*)d_in[3];  // [512,512]
    const float* proj_b       = (const float*)d_in[4];  // [512]
    const float* heads_W      = (const float*)d_in[5];  // [21,32000,512]
    const float* heads_b      = (const float*)d_in[6];  // [21,32000]
    float* out = (float*)d_out;                         // [8,128,32000]

    // workspace layout: [0,16KB) linfo fp32 [8,512]; [16KB, 16KB+1MB) enhanced bf16 [8,128,512]
    float* linfo = (float*)d_ws;
    short* enh   = (short*)((char*)d_ws + 16384);

    // 1) linfo: 4096 waves -> 1024 blocks x 256
    linfo_kernel<<<dim3(1024), dim3(256), 0, stream>>>(answer_len, length_table,
                                                       proj_W, proj_b, linfo);
    // 2) enhanced bf16: 524288 elems / 4 per thread / 256 = 512 blocks
    enh_kernel<<<dim3(512), dim3(256), 0, stream>>>(hidden, linfo, enh);
    // 3) GEMM: (V/128, B)
    gemm_kernel<<<dim3(Vn / 128, Bn), dim3(256), 0, stream>>>(enh, heads_W,
                                                              heads_b, answer_len, out);
}